// Round 1
// baseline (28.307 us; speedup 1.0000x reference)
//
#include <hip/hip_runtime.h>
#include <math.h>

// Camera projection for 2M gaussians.
// Memory-bound: 96MB in + 64MB out => ~25us floor @ 6.3TB/s.
// Output layout (flat f32): pos2d[N*3] | cov2d[N*4] | mask[N]

__global__ __launch_bounds__(256) void camera_kernel(
    const float* __restrict__ pos3d,   // (N,3)
    const float* __restrict__ cov3d,   // (N,3,3)
    const float* __restrict__ w2m,     // (4,4)
    float* __restrict__ pos2d,         // (N,3)
    float* __restrict__ cov2d,         // (N,2,2) -> float4 per point
    float* __restrict__ maskf,         // (N,)
    int n, float fx, float fy, float pA, float pB)
{
    int i = blockIdx.x * blockDim.x + threadIdx.x;
    if (i >= n) return;

    // Wave-uniform rotation/translation (scalar loads, broadcast).
    const float R00 = w2m[0], R01 = w2m[1], R02 = w2m[2],  t0 = w2m[3];
    const float R10 = w2m[4], R11 = w2m[5], R12 = w2m[6],  t1 = w2m[7];
    const float R20 = w2m[8], R21 = w2m[9], R22 = w2m[10], t2 = w2m[11];

    const float x = pos3d[3*i + 0];
    const float y = pos3d[3*i + 1];
    const float z = pos3d[3*i + 2];

    // p_model = R*p + t
    const float pmx = R00*x + R01*y + R02*z + t0;
    const float pmy = R10*x + R11*y + R12*z + t1;
    const float pmz = R20*x + R21*y + R22*z + t2;

    // clip = (fx*pmx, fy*pmy, pA*pmz + pB, pmz); ndc = clip.xyz / (clip.w + 1e-6)
    const float invw = 1.0f / (pmz + 1e-6f);
    const float ndcx = fx * pmx * invw;
    const float ndcy = fy * pmy * invw;
    const float ndcz = (pA * pmz + pB) * invw;

    const bool m = (ndcz >= 0.2f) && (ndcx >= -1.3f) && (ndcx <= 1.3f)
                                  && (ndcy >= -1.3f) && (ndcy <= 1.3f);

    const float px = 0.5f * (ndcx + 1.0f) * 1920.0f;
    const float py = (1.0f - 0.5f * (ndcy + 1.0f)) * 1080.0f;

    pos2d[3*i + 0] = m ? px   : 0.0f;
    pos2d[3*i + 1] = m ? py   : 0.0f;
    pos2d[3*i + 2] = m ? ndcz : 0.0f;

    // J uses ORIGINAL pos3d (per reference), Wm = R^T.
    // M[0][k] = invz*(R[k][0] - x*R[k][2]); M[1][k] = invz*(R[k][1] - y*R[k][2])
    const float invz = 1.0f / z;
    const float M00 = invz * (R00 - x * R02);
    const float M01 = invz * (R10 - x * R12);
    const float M02 = invz * (R20 - x * R22);
    const float M10 = invz * (R01 - y * R02);
    const float M11 = invz * (R11 - y * R12);
    const float M12 = invz * (R21 - y * R22);

    const float c00 = cov3d[9*i + 0], c01 = cov3d[9*i + 1], c02 = cov3d[9*i + 2];
    const float c10 = cov3d[9*i + 3], c11 = cov3d[9*i + 4], c12 = cov3d[9*i + 5];
    const float c20 = cov3d[9*i + 6], c21 = cov3d[9*i + 7], c22 = cov3d[9*i + 8];

    // T = M * C (2x3)
    const float T00 = M00*c00 + M01*c10 + M02*c20;
    const float T01 = M00*c01 + M01*c11 + M02*c21;
    const float T02 = M00*c02 + M01*c12 + M02*c22;
    const float T10 = M10*c00 + M11*c10 + M12*c20;
    const float T11 = M10*c01 + M11*c11 + M12*c21;
    const float T12 = M10*c02 + M11*c12 + M12*c22;

    // cov2d = T * M^T (2x2)
    float4 cv;
    cv.x = m ? (T00*M00 + T01*M01 + T02*M02) : 0.0f;
    cv.y = m ? (T00*M10 + T01*M11 + T02*M12) : 0.0f;
    cv.z = m ? (T10*M00 + T11*M01 + T12*M02) : 0.0f;
    cv.w = m ? (T10*M10 + T11*M11 + T12*M12) : 0.0f;
    reinterpret_cast<float4*>(cov2d)[i] = cv;

    maskf[i] = m ? 1.0f : 0.0f;
}

extern "C" void kernel_launch(void* const* d_in, const int* in_sizes, int n_in,
                              void* d_out, int out_size, void* d_ws, size_t ws_size,
                              hipStream_t stream) {
    const float* pos3d = (const float*)d_in[0];
    const float* cov3d = (const float*)d_in[1];
    const float* w2m   = (const float*)d_in[2];

    const int n = in_sizes[0] / 3;

    float* out   = (float*)d_out;
    float* pos2d = out;            // n*3
    float* cov2d = out + 3*(size_t)n;      // n*4
    float* maskf = out + 7*(size_t)n;      // n

    // Projection constants in double, cast to float (matches reference fp32 matrix).
    const double right = 0.1 * tan(0.5 * 1.2);
    const double top   = 0.1 * tan(0.5 * 0.9);
    const float fx = (float)(2.0 * 0.1 / (2.0 * right));
    const float fy = (float)(2.0 * 0.1 / (2.0 * top));
    const float pA = (float)(100.0 / (100.0 - 0.1));
    const float pB = (float)(-100.0 * 0.1 / (100.0 - 0.1));

    const int block = 256;
    const int grid = (n + block - 1) / block;
    camera_kernel<<<grid, block, 0, stream>>>(pos3d, cov3d, w2m,
                                              pos2d, cov2d, maskf,
                                              n, fx, fy, pA, pB);
}